// Round 6
// baseline (489.333 us; speedup 1.0000x reference)
//
#include <hip/hip_runtime.h>
#include <hip/hip_bf16.h>
#include <hip/hip_fp8.h>
#include <cstdint>
#include <cstddef>

// ---------------- problem constants ----------------
#define M_TOK 4096          // B*S = 4*1024 tokens
#define HID   1024
#define NHEAD 16002
#define NHEAD_PAD 16128     // 126*128
#define P0    256
#define N0    12000
#define N0_PAD 12032        // 94*128
#define P1    64
#define N1    8000
#define N1_PAD 8064         // 63*128
#define PFUSE 384           // fused proj width: 256 + 128(pad of 64)
#define PREAL 320           // real cols in fused proj: 256 + 64

typedef unsigned char u8;
typedef float f32x16 __attribute__((ext_vector_type(16)));
typedef int   i32x4  __attribute__((ext_vector_type(4)));
typedef int   i32x8  __attribute__((ext_vector_type(8)));

// async global->LDS, 16B per lane; lds ptr = wave-uniform base, HW scatters lane*16.
__device__ __forceinline__ void load16(const void* g, void* l) {
    __builtin_amdgcn_global_load_lds(
        (__attribute__((address_space(1))) void*)g,
        (__attribute__((address_space(3))) void*)l,
        16, 0, 0);
}

__device__ __forceinline__ u8 to_e4m3(float f) {
    __hip_fp8_e4m3 h(f);
    return (u8)h.__x;
}

// ---------------- cast inp f32 -> fp8 e4m3 ----------------
__global__ void cast_kernel(const float* __restrict__ src, u8* __restrict__ dst8, int n4) {
    int i = blockIdx.x * blockDim.x + threadIdx.x;
    if (i < n4) {
        float4 v = reinterpret_cast<const float4*>(src)[i];
        uchar4 o8;
        o8.x = to_e4m3(v.x); o8.y = to_e4m3(v.y); o8.z = to_e4m3(v.z); o8.w = to_e4m3(v.w);
        reinterpret_cast<uchar4*>(dst8)[i] = o8;
    }
}

// ---------------- tiled transpose: f32 (K x N) -> fp8 (Npad x Kpad), pre-scaled ----------------
// grid.x covers Npad/32, grid.y covers Kpad/64; zero-fills k>=K and n>=N.
__global__ void transpose_pad_fp8(const float* __restrict__ W, u8* __restrict__ WT,
                                  int K, int N, int Kpad, float scale) {
    __shared__ float tile[64][33];
    int n0 = blockIdx.x * 32, k0 = blockIdx.y * 64;
    int tx = threadIdx.x & 31, ty = threadIdx.x >> 5;   // 32 x 8
    #pragma unroll
    for (int i = 0; i < 8; i++) {
        int k = k0 + ty + i * 8, n = n0 + tx;
        tile[ty + i * 8][tx] = (k < K && n < N) ? W[(size_t)k * N + n] * scale : 0.0f;
    }
    __syncthreads();
    int n = threadIdx.x >> 3, kc = threadIdx.x & 7;     // n 0..31, kc 0..7
    union { u8 b[8]; uint2 u; } v;
    #pragma unroll
    for (int j = 0; j < 8; j++) v.b[j] = to_e4m3(tile[kc * 8 + j][n]);
    *reinterpret_cast<uint2*>(WT + (size_t)(n0 + n) * Kpad + k0 + kc * 8) = v.u;
}

// ---------------- init: zero accumulators + out, targets, fused proj bias ----------------
__global__ void init_kernel(const int* __restrict__ labels, float* __restrict__ acc6,
                            int* __restrict__ tgts, float* __restrict__ out,
                            const float* __restrict__ t0_pb, const float* __restrict__ t1_pb,
                            float* __restrict__ pbias) {
    int t = blockIdx.x * blockDim.x + threadIdx.x;   // 4096 threads
    for (int j = t; j < 6 * M_TOK; j += M_TOK) acc6[j] = 0.0f;
    if (t == 0) out[0] = 0.0f;
    if (t < PFUSE) pbias[t] = (t < 256) ? t0_pb[t] : ((t < PREAL) ? t1_pb[t - 256] : 0.0f);
    int lbl = labels[t];
    tgts[t]             = (lbl < 16000) ? lbl : ((lbl < 28000) ? 16000 : 16001);
    int t0 = lbl - 16000; t0 = t0 < 0 ? 0 : (t0 > 11999 ? 11999 : t0);
    int t1 = lbl - 28000; t1 = t1 < 0 ? 0 : (t1 > 7999  ? 7999  : t1);
    tgts[M_TOK + t]     = t0;
    tgts[2 * M_TOK + t] = t1;
}

// ---------------- unified MX-fp8 GEMM: C = A(M x K, lda) * BT(Npad x K, ldb)^T ----------------
// mfma_scale_f32_32x32x64_f8f6f4, A-scale 1.0, B-scale 2^-5 (weights pre-scaled x32).
// Block 128x128, BK=64, 4 waves 2x2, wave 64x64 via 2x2 MFMAs of 32x32x64.
// LDS: 64B rows (4 granules), phys granule = row*4 + (gcol ^ ((row>>1)&3))
//   -- exact R4 geometry, measured 0 bank conflicts.
// LSE epilogue: sumexp += exp(logit) (col<realN), label-logit capture.
// STORE epilogue: out[tok*ldo+col] = e4m3(acc+bias) (pad cols -> 0).
template <bool LSEP>
__launch_bounds__(256, 2)
__global__ void gemm_fp8(const u8* __restrict__ A, int lda,
                         const u8* __restrict__ BT, int ldb,
                         const float* __restrict__ bias, int K, int realN,
                         const int* __restrict__ tgt, float* __restrict__ sumexp,
                         float* __restrict__ lab, u8* __restrict__ out, int ldo) {
    __shared__ __align__(16) u8 As[128 * 64];
    __shared__ __align__(16) u8 Bs[128 * 64];

    const int tid  = threadIdx.x;
    const int lane = tid & 63;
    const int wave = tid >> 6;
    const int wm = wave >> 1, wn = wave & 1;
    const int h = lane >> 5;            // k-half for MFMA operand
    const int ln32 = lane & 31;
    const int m0 = blockIdx.x * 128, n0 = blockIdx.y * 128;

    // staging: physical granule g = wave*128 + p*64 + lane (512 per tile);
    // row = g>>2, c = g&3, logical gcol = c ^ ((row>>1)&3); global ofs = row*ld + gcol*16.
    int aofs[2], bofs[2];
    #pragma unroll
    for (int p = 0; p < 2; p++) {
        int g = wave * 128 + p * 64 + lane;
        int row = g >> 2, c = g & 3;
        int gcol = c ^ ((row >> 1) & 3);
        aofs[p] = row * lda + gcol * 16;
        bofs[p] = row * ldb + gcol * 16;
    }

    f32x16 acc[2][2];
    #pragma unroll
    for (int mt = 0; mt < 2; mt++)
        #pragma unroll
        for (int nt = 0; nt < 2; nt++)
            acc[mt][nt] = (f32x16)(0.0f);

    const u8* Ab = A  + (size_t)m0 * lda;
    const u8* Bb = BT + (size_t)n0 * ldb;

    union Frag { struct { i32x4 lo, hi; } half; i32x8 v; };

    for (int k0 = 0; k0 < K; k0 += 64) {
        #pragma unroll
        for (int p = 0; p < 2; p++) {
            int base = (wave * 128 + p * 64) * 16;   // wave-uniform LDS byte offset
            load16(Ab + k0 + aofs[p], As + base);
            load16(Bb + k0 + bofs[p], Bs + base);
        }
        __syncthreads();
        Frag fa[2], fb[2];
        #pragma unroll
        for (int t = 0; t < 2; t++) {
            int mA = wm * 64 + t * 32 + ln32;
            int swA = (mA >> 1) & 3;
            fa[t].half.lo = *reinterpret_cast<const i32x4*>(As + (mA * 4 + ((h * 2)     ^ swA)) * 16);
            fa[t].half.hi = *reinterpret_cast<const i32x4*>(As + (mA * 4 + ((h * 2 + 1) ^ swA)) * 16);
            int mB = wn * 64 + t * 32 + ln32;
            int swB = (mB >> 1) & 3;
            fb[t].half.lo = *reinterpret_cast<const i32x4*>(Bs + (mB * 4 + ((h * 2)     ^ swB)) * 16);
            fb[t].half.hi = *reinterpret_cast<const i32x4*>(Bs + (mB * 4 + ((h * 2 + 1) ^ swB)) * 16);
        }
        #pragma unroll
        for (int mt = 0; mt < 2; mt++)
            #pragma unroll
            for (int nt = 0; nt < 2; nt++)
                acc[mt][nt] = __builtin_amdgcn_mfma_scale_f32_32x32x64_f8f6f4(
                    fa[mt].v, fb[nt].v, acc[mt][nt],
                    0, 0,                      // cbsz=fp8(e4m3), blgp=fp8(e4m3)
                    0, 0x7F7F7F7F,             // A scale: 2^0
                    0, 0x7A7A7A7A);            // B scale: 2^-5
        __syncthreads();
    }

    // C/D layout (32x32): col = lane&31, row = (reg&3) + 8*(reg>>2) + 4*(lane>>5)
    int colg[2]; float bias_v[2];
    #pragma unroll
    for (int nt = 0; nt < 2; nt++) {
        colg[nt] = n0 + wn * 64 + nt * 32 + ln32;
        bias_v[nt] = (colg[nt] < realN) ? bias[colg[nt]] : 0.0f;
    }

    #pragma unroll
    for (int mt = 0; mt < 2; mt++) {
        #pragma unroll
        for (int rg = 0; rg < 16; rg++) {
            int tok = m0 + wm * 64 + mt * 32 + (rg & 3) + 8 * (rg >> 2) + 4 * h;
            if constexpr (LSEP) {
                int tg = tgt[tok];
                float s = 0.0f;
                #pragma unroll
                for (int nt = 0; nt < 2; nt++) {
                    if (colg[nt] < realN) {
                        float logit = acc[mt][nt][rg] + bias_v[nt];
                        s += __expf(logit);
                        if (colg[nt] == tg) atomicAdd(&lab[tok], logit);
                    }
                }
                s += __shfl_xor(s, 1);
                s += __shfl_xor(s, 2);
                s += __shfl_xor(s, 4);
                s += __shfl_xor(s, 8);
                s += __shfl_xor(s, 16);
                if (ln32 == 0) atomicAdd(&sumexp[tok], s);
            } else {
                #pragma unroll
                for (int nt = 0; nt < 2; nt++)
                    out[(size_t)tok * ldo + colg[nt]] = to_e4m3(acc[mt][nt][rg] + bias_v[nt]);
            }
        }
    }
}

// ---------------- finalize: per-token loss, mask, mean ----------------
__global__ void finalize_kernel(const int* __restrict__ labels, const float* __restrict__ acc6,
                                float* __restrict__ out) {
    int t = blockIdx.x * blockDim.x + threadIdx.x;   // 4096 threads
    const float* sumH = acc6;
    const float* labH = acc6 + M_TOK;
    const float* sum0 = acc6 + 2 * M_TOK;
    const float* lab0 = acc6 + 3 * M_TOK;
    const float* sum1 = acc6 + 4 * M_TOK;
    const float* lab1 = acc6 + 5 * M_TOK;
    int lbl = labels[t];
    float l = 0.0f;
    if (lbl != 0) {
        l = logf(sumH[t]) - labH[t];
        if (lbl >= 16000 && lbl < 28000) l += logf(sum0[t]) - lab0[t];
        else if (lbl >= 28000)           l += logf(sum1[t]) - lab1[t];
    }
    l *= (1.0f / (float)M_TOK);
    #pragma unroll
    for (int off = 1; off < 64; off <<= 1) l += __shfl_xor(l, off);
    __shared__ float red[4];
    if ((threadIdx.x & 63) == 0) red[threadIdx.x >> 6] = l;
    __syncthreads();
    if (threadIdx.x == 0) atomicAdd(out, red[0] + red[1] + red[2] + red[3]);
}

// ---------------- host launcher ----------------
extern "C" void kernel_launch(void* const* d_in, const int* in_sizes, int n_in,
                              void* d_out, int out_size, void* d_ws, size_t ws_size,
                              hipStream_t stream) {
    const float* inp    = (const float*)d_in[0];
    const int*   labels = (const int*)  d_in[1];
    const float* head_W = (const float*)d_in[2];
    const float* head_b = (const float*)d_in[3];
    const float* t0_pW  = (const float*)d_in[4];
    const float* t0_pb  = (const float*)d_in[5];
    const float* t0_W   = (const float*)d_in[6];
    const float* t0_b   = (const float*)d_in[7];
    const float* t1_pW  = (const float*)d_in[8];
    const float* t1_pb  = (const float*)d_in[9];
    const float* t1_W   = (const float*)d_in[10];
    const float* t1_b   = (const float*)d_in[11];
    float* out = (float*)d_out;

    char* ws = (char*)d_ws;
    size_t off = 0;
    auto alloc = [&](size_t bytes) { char* p = ws + off; off += (bytes + 255) & ~(size_t)255; return p; };
    u8*    inp_f8  = (u8*)   alloc((size_t)M_TOK * HID);
    u8*    headW8  = (u8*)   alloc((size_t)NHEAD_PAD * HID);
    u8*    fpW8    = (u8*)   alloc((size_t)PFUSE * HID);         // fused proj weights^T
    u8*    t0W8    = (u8*)   alloc((size_t)N0_PAD * P0);
    u8*    t1W8    = (u8*)   alloc((size_t)N1_PAD * 128);        // K padded 64->128
    u8*    proj8   = (u8*)   alloc((size_t)M_TOK * PFUSE);
    float* acc6    = (float*)alloc(6 * M_TOK * 4);
    int*   tgts    = (int*)  alloc(3 * M_TOK * 4);
    float* pbias   = (float*)alloc(PFUSE * 4);

    // stage 1: conversions / transposes (weights pre-scaled x32, MFMA B-scale 2^-5)
    cast_kernel<<<(M_TOK * HID / 4 + 255) / 256, 256, 0, stream>>>(inp, inp_f8, M_TOK * HID / 4);
    transpose_pad_fp8<<<dim3(NHEAD_PAD / 32, HID / 64), 256, 0, stream>>>(head_W, headW8, HID, NHEAD, HID, 32.0f);
    transpose_pad_fp8<<<dim3(256 / 32, HID / 64), 256, 0, stream>>>(t0_pW, fpW8,              HID, P0, HID, 32.0f);
    transpose_pad_fp8<<<dim3(128 / 32, HID / 64), 256, 0, stream>>>(t1_pW, fpW8 + 256 * HID,  HID, P1, HID, 32.0f);
    transpose_pad_fp8<<<dim3(N0_PAD / 32, P0 / 64), 256, 0, stream>>>(t0_W, t0W8, P0, N0, P0, 32.0f);
    transpose_pad_fp8<<<dim3(N1_PAD / 32, 128 / 64), 256, 0, stream>>>(t1_W, t1W8, P1, N1, 128, 32.0f);
    init_kernel<<<M_TOK / 256, 256, 0, stream>>>(labels, acc6, tgts, out, t0_pb, t1_pb, pbias);

    // stage 2: fused tail projections -> fp8 [M_TOK x 384]
    gemm_fp8<false><<<dim3(M_TOK / 128, PFUSE / 128), 256, 0, stream>>>(
        inp_f8, HID, fpW8, HID, pbias, HID, PREAL, nullptr, nullptr, nullptr, proj8, PFUSE);

    // stage 3: logsumexp GEMMs
    gemm_fp8<true><<<dim3(M_TOK / 128, NHEAD_PAD / 128), 256, 0, stream>>>(
        inp_f8, HID, headW8, HID, head_b, HID, NHEAD, tgts, acc6, acc6 + M_TOK, nullptr, 0);
    gemm_fp8<true><<<dim3(M_TOK / 128, N0_PAD / 128), 256, 0, stream>>>(
        proj8, PFUSE, t0W8, P0, t0_b, P0, N0, tgts + M_TOK, acc6 + 2 * M_TOK, acc6 + 3 * M_TOK, nullptr, 0);
    gemm_fp8<true><<<dim3(M_TOK / 128, N1_PAD / 128), 256, 0, stream>>>(
        proj8 + 256, PFUSE, t1W8, 128, t1_b, 128, N1, tgts + 2 * M_TOK, acc6 + 4 * M_TOK, acc6 + 5 * M_TOK, nullptr, 0);

    // stage 4: reduce to scalar mean
    finalize_kernel<<<M_TOK / 256, 256, 0, stream>>>(labels, acc6, out);
}

// Round 7
// 405.886 us; speedup vs baseline: 1.2056x; 1.2056x over previous
//
#include <hip/hip_runtime.h>
#include <hip/hip_bf16.h>
#include <hip/hip_fp8.h>
#include <cstdint>
#include <cstddef>

// ---------------- problem constants ----------------
#define M_TOK 4096          // B*S = 4*1024 tokens
#define HID   1024
#define NHEAD 16002
#define NHEAD_PAD 16128     // 126*128
#define P0    256
#define N0    12000
#define N0_PAD 12032        // 94*128
#define P1    64
#define N1    8000
#define N1_PAD 8064         // 63*128
#define PFUSE 384           // fused proj width: 256 + 128(pad of 64)
#define PREAL 320           // real cols in fused proj: 256 + 64

typedef unsigned char u8;
typedef float f32x16 __attribute__((ext_vector_type(16)));
typedef int   i32x4  __attribute__((ext_vector_type(4)));
typedef int   i32x8  __attribute__((ext_vector_type(8)));

// async global->LDS, 16B per lane; lds ptr = wave-uniform base, HW scatters lane*16.
__device__ __forceinline__ void load16(const void* g, void* l) {
    __builtin_amdgcn_global_load_lds(
        (__attribute__((address_space(1))) void*)g,
        (__attribute__((address_space(3))) void*)l,
        16, 0, 0);
}

__device__ __forceinline__ u8 to_e4m3(float f) {
    __hip_fp8_e4m3 h(f);
    return (u8)h.__x;
}

// =====================================================================
// Unified MX-fp8 GEMM body: C = A(M x K, lda) * BT(N x K, ldb)^T
// mfma_scale_f32_32x32x64_f8f6f4; A-scale 1.0, B-scale 2^-5 (W pre-scaled x32).
// Block 128x128, BK=128 (two 64-byte k-planes per barrier -> R5 cadence:
// 8 global_load_lds/wave/iter, 8 MFMAs/wave/iter), 4 waves 2x2.
// LDS per matrix: plane-major [2][128 rows][64 B]; within a plane, physical
// granule = row*4 + (gcol ^ ((row>>1)&3))  (R4/R6 XOR geometry).
// =====================================================================
template <bool LSEP>
__device__ __forceinline__ void gemm_body(
        const u8* __restrict__ A, int lda, const u8* __restrict__ BT, int ldb,
        const float* __restrict__ bias, int K, int realN,
        const int* __restrict__ tgt, float* __restrict__ sumexp, float* __restrict__ lab,
        u8* __restrict__ out, int ldo, int m0, int n0,
        u8* As, u8* Bs) {
    const int tid  = threadIdx.x;
    const int lane = tid & 63;
    const int wave = tid >> 6;
    const int wm = wave >> 1, wn = wave & 1;
    const int h = lane >> 5;            // k-half within a plane
    const int ln32 = lane & 31;

    // staging: physical granule pg = wave*256 + l*64 + lane (l=0..3), 1024/matrix.
    // decode: plane = pg>>9, r4 = pg&511, row = r4>>2, c = r4&3,
    //         gcol = c ^ ((row>>1)&3); global ofs = row*ld + plane*64 + gcol*16.
    int aofs[4], bofs[4];
    #pragma unroll
    for (int l = 0; l < 4; l++) {
        int pg = wave * 256 + l * 64 + lane;
        int plane = pg >> 9, r4 = pg & 511;
        int row = r4 >> 2, c = r4 & 3;
        int gcol = c ^ ((row >> 1) & 3);
        aofs[l] = row * lda + plane * 64 + gcol * 16;
        bofs[l] = row * ldb + plane * 64 + gcol * 16;
    }

    f32x16 acc[2][2];
    #pragma unroll
    for (int mt = 0; mt < 2; mt++)
        #pragma unroll
        for (int nt = 0; nt < 2; nt++)
            acc[mt][nt] = (f32x16)(0.0f);

    const u8* Ab = A  + (size_t)m0 * lda;
    const u8* Bb = BT + (size_t)n0 * ldb;

    union Frag { struct { i32x4 lo, hi; } half; i32x8 v; };

    for (int k0 = 0; k0 < K; k0 += 128) {
        #pragma unroll
        for (int l = 0; l < 4; l++) {
            int base = (wave * 256 + l * 64) * 16;   // wave-uniform LDS byte offset
            load16(Ab + k0 + aofs[l], As + base);
            load16(Bb + k0 + bofs[l], Bs + base);
        }
        __syncthreads();
        #pragma unroll
        for (int ks = 0; ks < 2; ks++) {
            Frag fa[2], fb[2];
            #pragma unroll
            for (int t = 0; t < 2; t++) {
                int mA = wm * 64 + t * 32 + ln32;
                int swA = (mA >> 1) & 3;
                fa[t].half.lo = *reinterpret_cast<const i32x4*>(As + (ks * 512 + mA * 4 + ((h * 2)     ^ swA)) * 16);
                fa[t].half.hi = *reinterpret_cast<const i32x4*>(As + (ks * 512 + mA * 4 + ((h * 2 + 1) ^ swA)) * 16);
                int mB = wn * 64 + t * 32 + ln32;
                int swB = (mB >> 1) & 3;
                fb[t].half.lo = *reinterpret_cast<const i32x4*>(Bs + (ks * 512 + mB * 4 + ((h * 2)     ^ swB)) * 16);
                fb[t].half.hi = *reinterpret_cast<const i32x4*>(Bs + (ks * 512 + mB * 4 + ((h * 2 + 1) ^ swB)) * 16);
            }
            #pragma unroll
            for (int mt = 0; mt < 2; mt++)
                #pragma unroll
                for (int nt = 0; nt < 2; nt++)
                    acc[mt][nt] = __builtin_amdgcn_mfma_scale_f32_32x32x64_f8f6f4(
                        fa[mt].v, fb[nt].v, acc[mt][nt],
                        0, 0,                      // cbsz/blgp = fp8 e4m3
                        0, 0x7F7F7F7F,             // A scale: 2^0
                        0, 0x7A7A7A7A);            // B scale: 2^-5
        }
        __syncthreads();
    }

    // C/D layout (32x32): col = lane&31, row = (reg&3) + 8*(reg>>2) + 4*(lane>>5)
    int colg[2]; float bias_v[2];
    #pragma unroll
    for (int nt = 0; nt < 2; nt++) {
        colg[nt] = n0 + wn * 64 + nt * 32 + ln32;
        bias_v[nt] = (colg[nt] < realN) ? bias[colg[nt]] : 0.0f;
    }

    #pragma unroll
    for (int mt = 0; mt < 2; mt++) {
        #pragma unroll
        for (int rg = 0; rg < 16; rg++) {
            int tok = m0 + wm * 64 + mt * 32 + (rg & 3) + 8 * (rg >> 2) + 4 * h;
            if constexpr (LSEP) {
                int tg = tgt[tok];
                float s = 0.0f;
                #pragma unroll
                for (int nt = 0; nt < 2; nt++) {
                    if (colg[nt] < realN) {
                        float logit = acc[mt][nt][rg] + bias_v[nt];
                        s += __expf(logit);
                        if (colg[nt] == tg) atomicAdd(&lab[tok], logit);
                    }
                }
                s += __shfl_xor(s, 1);
                s += __shfl_xor(s, 2);
                s += __shfl_xor(s, 4);
                s += __shfl_xor(s, 8);
                s += __shfl_xor(s, 16);
                if (ln32 == 0) atomicAdd(&sumexp[tok], s);
            } else {
                #pragma unroll
                for (int nt = 0; nt < 2; nt++)
                    out[(size_t)tok * ldo + colg[nt]] = to_e4m3(acc[mt][nt][rg] + bias_v[nt]);
            }
        }
    }
}

// ---------------- proj GEMM (store epilogue) ----------------
__launch_bounds__(256, 2)
__global__ void gemm_proj(const u8* __restrict__ A, const u8* __restrict__ BT,
                          const float* __restrict__ bias, u8* __restrict__ out) {
    __shared__ __align__(16) u8 As[16384];
    __shared__ __align__(16) u8 Bs[16384];
    gemm_body<false>(A, HID, BT, HID, bias, HID, PREAL,
                     nullptr, nullptr, nullptr, out, PFUSE,
                     blockIdx.x * 128, blockIdx.y * 128, As, Bs);
}

// ---------------- fused LSE GEMM: head + tail0 + tail1 in one dispatch ----------------
struct Seg {
    const u8* A; int lda;
    const u8* BT; int ldb;
    const float* bias; int K; int realN;
    const int* tgt; float* sumexp; float* lab;
    int nblk;
};

__launch_bounds__(256, 2)
__global__ void gemm_lse3(Seg s0, Seg s1, Seg s2) {
    __shared__ __align__(16) u8 As[16384];
    __shared__ __align__(16) u8 Bs[16384];
    int b = blockIdx.x;
    Seg s; int rel;
    if (b < s0.nblk)                { s = s0; rel = b; }
    else if (b < s0.nblk + s1.nblk) { s = s1; rel = b - s0.nblk; }
    else                            { s = s2; rel = b - s0.nblk - s1.nblk; }
    int m0 = (rel & 31) * 128, n0 = (rel >> 5) * 128;
    gemm_body<true>(s.A, s.lda, s.BT, s.ldb, s.bias, s.K, s.realN,
                    s.tgt, s.sumexp, s.lab, nullptr, 0, m0, n0, As, Bs);
}

// =====================================================================
// prep: all casts/transposes/init fused into one dispatch (branch by range)
// =====================================================================
__device__ __forceinline__ void do_transpose(const float* __restrict__ W, u8* __restrict__ WT,
                                             int K, int N, int Kpad, float scale,
                                             int bx, int by, float (*tile)[33]) {
    int n0 = bx * 32, k0 = by * 64;
    int tx = threadIdx.x & 31, ty = threadIdx.x >> 5;   // 32 x 8
    #pragma unroll
    for (int i = 0; i < 8; i++) {
        int k = k0 + ty + i * 8, n = n0 + tx;
        tile[ty + i * 8][tx] = (k < K && n < N) ? W[(size_t)k * N + n] * scale : 0.0f;
    }
    __syncthreads();
    int n = threadIdx.x >> 3, kc = threadIdx.x & 7;     // n 0..31, kc 0..7
    union { u8 b[8]; uint2 u; } v;
    #pragma unroll
    for (int j = 0; j < 8; j++) v.b[j] = to_e4m3(tile[kc * 8 + j][n]);
    *reinterpret_cast<uint2*>(WT + (size_t)(n0 + n) * Kpad + k0 + kc * 8) = v.u;
}

#define NB_HEADT 8064   // 504 x 16
#define NB_T0W   1504   // 376 x 4
#define NB_CAST  1024
#define NB_T1W    504   // 252 x 2
#define NB_T0P    128   // 8 x 16
#define NB_T1P     64   // 4 x 16
#define NB_INIT    16

__global__ void prep_kernel(const float* __restrict__ inp, const int* __restrict__ labels,
                            const float* __restrict__ head_W,
                            const float* __restrict__ t0_pW, const float* __restrict__ t0_pb,
                            const float* __restrict__ t0_W,
                            const float* __restrict__ t1_pW, const float* __restrict__ t1_pb,
                            const float* __restrict__ t1_W,
                            u8* __restrict__ inp_f8, u8* __restrict__ headW8,
                            u8* __restrict__ fpW8, u8* __restrict__ t0W8, u8* __restrict__ t1W8,
                            float* __restrict__ acc6, int* __restrict__ tgts,
                            float* __restrict__ pbias, float* __restrict__ out) {
    __shared__ float tile[64][33];
    int b = blockIdx.x;
    if (b < NB_HEADT) {
        do_transpose(head_W, headW8, HID, NHEAD, HID, 32.0f, b % 504, b / 504, tile);
    } else if (b < NB_HEADT + NB_T0W) {
        int r = b - NB_HEADT;
        do_transpose(t0_W, t0W8, P0, N0, P0, 32.0f, r % 376, r / 376, tile);
    } else if (b < NB_HEADT + NB_T0W + NB_CAST) {
        int r = b - (NB_HEADT + NB_T0W);
        int i = r * 256 + threadIdx.x;          // i < 262144 = M_TOK*HID/4
        float4 v = reinterpret_cast<const float4*>(inp)[i];
        uchar4 o8;
        o8.x = to_e4m3(v.x); o8.y = to_e4m3(v.y); o8.z = to_e4m3(v.z); o8.w = to_e4m3(v.w);
        reinterpret_cast<uchar4*>(inp_f8)[i] = o8;
    } else if (b < NB_HEADT + NB_T0W + NB_CAST + NB_T1W) {
        int r = b - (NB_HEADT + NB_T0W + NB_CAST);
        do_transpose(t1_W, t1W8, P1, N1, 128, 32.0f, r % 252, r / 252, tile);
    } else if (b < NB_HEADT + NB_T0W + NB_CAST + NB_T1W + NB_T0P) {
        int r = b - (NB_HEADT + NB_T0W + NB_CAST + NB_T1W);
        do_transpose(t0_pW, fpW8, HID, P0, HID, 32.0f, r % 8, r / 8, tile);
    } else if (b < NB_HEADT + NB_T0W + NB_CAST + NB_T1W + NB_T0P + NB_T1P) {
        int r = b - (NB_HEADT + NB_T0W + NB_CAST + NB_T1W + NB_T0P);
        do_transpose(t1_pW, fpW8 + 256 * HID, HID, P1, HID, 32.0f, r % 4, r / 4, tile);
    } else {
        int r = b - (NB_HEADT + NB_T0W + NB_CAST + NB_T1W + NB_T0P + NB_T1P);
        int t = r * 256 + threadIdx.x;          // t < 4096
        for (int j = t; j < 6 * M_TOK; j += M_TOK) acc6[j] = 0.0f;
        if (t == 0) out[0] = 0.0f;
        if (t < PFUSE) pbias[t] = (t < 256) ? t0_pb[t] : ((t < PREAL) ? t1_pb[t - 256] : 0.0f);
        int lbl = labels[t];
        tgts[t]             = (lbl < 16000) ? lbl : ((lbl < 28000) ? 16000 : 16001);
        int t0 = lbl - 16000; t0 = t0 < 0 ? 0 : (t0 > 11999 ? 11999 : t0);
        int t1 = lbl - 28000; t1 = t1 < 0 ? 0 : (t1 > 7999  ? 7999  : t1);
        tgts[M_TOK + t]     = t0;
        tgts[2 * M_TOK + t] = t1;
    }
}

// ---------------- finalize: per-token loss, mask, mean ----------------
__global__ void finalize_kernel(const int* __restrict__ labels, const float* __restrict__ acc6,
                                float* __restrict__ out) {
    int t = blockIdx.x * blockDim.x + threadIdx.x;   // 4096 threads
    const float* sumH = acc6;
    const float* labH = acc6 + M_TOK;
    const float* sum0 = acc6 + 2 * M_TOK;
    const float* lab0 = acc6 + 3 * M_TOK;
    const float* sum1 = acc6 + 4 * M_TOK;
    const float* lab1 = acc6 + 5 * M_TOK;
    int lbl = labels[t];
    float l = 0.0f;
    if (lbl != 0) {
        l = logf(sumH[t]) - labH[t];
        if (lbl >= 16000 && lbl < 28000) l += logf(sum0[t]) - lab0[t];
        else if (lbl >= 28000)           l += logf(sum1[t]) - lab1[t];
    }
    l *= (1.0f / (float)M_TOK);
    #pragma unroll
    for (int off = 1; off < 64; off <<= 1) l += __shfl_xor(l, off);
    __shared__ float red[4];
    if ((threadIdx.x & 63) == 0) red[threadIdx.x >> 6] = l;
    __syncthreads();
    if (threadIdx.x == 0) atomicAdd(out, red[0] + red[1] + red[2] + red[3]);
}

// ---------------- host launcher ----------------
extern "C" void kernel_launch(void* const* d_in, const int* in_sizes, int n_in,
                              void* d_out, int out_size, void* d_ws, size_t ws_size,
                              hipStream_t stream) {
    const float* inp    = (const float*)d_in[0];
    const int*   labels = (const int*)  d_in[1];
    const float* head_W = (const float*)d_in[2];
    const float* head_b = (const float*)d_in[3];
    const float* t0_pW  = (const float*)d_in[4];
    const float* t0_pb  = (const float*)d_in[5];
    const float* t0_W   = (const float*)d_in[6];
    const float* t0_b   = (const float*)d_in[7];
    const float* t1_pW  = (const float*)d_in[8];
    const float* t1_pb  = (const float*)d_in[9];
    const float* t1_W   = (const float*)d_in[10];
    const float* t1_b   = (const float*)d_in[11];
    float* out = (float*)d_out;

    char* ws = (char*)d_ws;
    size_t off = 0;
    auto alloc = [&](size_t bytes) { char* p = ws + off; off += (bytes + 255) & ~(size_t)255; return p; };
    u8*    inp_f8  = (u8*)   alloc((size_t)M_TOK * HID);
    u8*    headW8  = (u8*)   alloc((size_t)NHEAD_PAD * HID);
    u8*    fpW8    = (u8*)   alloc((size_t)PFUSE * HID);
    u8*    t0W8    = (u8*)   alloc((size_t)N0_PAD * P0);
    u8*    t1W8    = (u8*)   alloc((size_t)N1_PAD * 128);
    u8*    proj8   = (u8*)   alloc((size_t)M_TOK * PFUSE);
    float* acc6    = (float*)alloc(6 * M_TOK * 4);
    int*   tgts    = (int*)  alloc(3 * M_TOK * 4);
    float* pbias   = (float*)alloc(PFUSE * 4);

    // stage 1: all conversions / transposes / init in one dispatch
    int nb = NB_HEADT + NB_T0W + NB_CAST + NB_T1W + NB_T0P + NB_T1P + NB_INIT;
    prep_kernel<<<nb, 256, 0, stream>>>(inp, labels, head_W, t0_pW, t0_pb, t0_W,
                                        t1_pW, t1_pb, t1_W,
                                        inp_f8, headW8, fpW8, t0W8, t1W8,
                                        acc6, tgts, pbias, out);

    // stage 2: fused tail projections -> fp8 [M_TOK x 384]
    gemm_proj<<<dim3(M_TOK / 128, PFUSE / 128), 256, 0, stream>>>(inp_f8, fpW8, pbias, proj8);

    // stage 3: all three LSE GEMMs in one dispatch (head first = longest)
    Seg s0{inp_f8,      HID,   headW8, HID, head_b, HID, NHEAD, tgts,             acc6,             acc6 + M_TOK,     32 * (NHEAD_PAD / 128)};
    Seg s1{proj8,       PFUSE, t0W8,   P0,  t0_b,   P0,  N0,    tgts + M_TOK,     acc6 + 2 * M_TOK, acc6 + 3 * M_TOK, 32 * (N0_PAD / 128)};
    Seg s2{proj8 + 256, PFUSE, t1W8,   128, t1_b,   128, N1,    tgts + 2 * M_TOK, acc6 + 4 * M_TOK, acc6 + 5 * M_TOK, 32 * (N1_PAD / 128)};
    gemm_lse3<<<s0.nblk + s1.nblk + s2.nblk, 256, 0, stream>>>(s0, s1, s2);

    // stage 4: reduce to scalar mean
    finalize_kernel<<<M_TOK / 256, 256, 0, stream>>>(labels, acc6, out);
}

// Round 8
// 377.098 us; speedup vs baseline: 1.2976x; 1.0763x over previous
//
#include <hip/hip_runtime.h>
#include <hip/hip_bf16.h>
#include <hip/hip_fp8.h>
#include <cstdint>
#include <cstddef>

// ---------------- problem constants ----------------
#define M_TOK 4096          // B*S = 4*1024 tokens
#define HID   1024
#define NHEAD 16002
#define NHEAD_PAD 16128     // 126*128
#define P0    256
#define N0    12000
#define N0_PAD 12032        // 94*128
#define P1    64
#define N1    8000
#define N1_PAD 8064         // 63*128
#define PFUSE 384           // fused proj width: 256 + 128(pad of 64)
#define PREAL 320           // real cols in fused proj: 256 + 64

typedef unsigned char u8;
typedef float f32x4 __attribute__((ext_vector_type(4)));
typedef int   i32x4 __attribute__((ext_vector_type(4)));
typedef int   i32x8 __attribute__((ext_vector_type(8)));

// async global->LDS, 16B per lane; lds ptr = wave-uniform base, HW scatters lane*16.
__device__ __forceinline__ void load16(const void* g, void* l) {
    __builtin_amdgcn_global_load_lds(
        (__attribute__((address_space(1))) void*)g,
        (__attribute__((address_space(3))) void*)l,
        16, 0, 0);
}

__device__ __forceinline__ u8 to_e4m3(float f) {
    __hip_fp8_e4m3 h(f);
    return (u8)h.__x;
}

// =====================================================================
// Unified MX-fp8 GEMM body: C = A(M x K, lda) * BT(N x K, ldb)^T
// mfma_scale_f32_16x16x128_f8f6f4 (R5-verified); A-scale 1.0, B-scale 2^-5.
// Block 128x128, BK=128, 4 waves 2x2, wave 64x64 via 4x4 MFMAs (16 indep chains).
// LDS per matrix: flat 128 rows x 128 B; physical granule = row*8 + (gcol ^ (row&7)).
// =====================================================================
template <bool LSEP>
__device__ __forceinline__ void gemm_body(
        const u8* __restrict__ A, int lda, const u8* __restrict__ BT, int ldb,
        const float* __restrict__ bias, int K, int realN,
        const int* __restrict__ tgt, float* __restrict__ sumexp, float* __restrict__ lab,
        u8* __restrict__ out, int ldo, int m0, int n0,
        u8* As, u8* Bs) {
    const int tid  = threadIdx.x;
    const int lane = tid & 63;
    const int wave = tid >> 6;
    const int wm = wave >> 1, wn = wave & 1;
    const int q = lane >> 4, lrow = lane & 15;

    // staging: physical granule pg = wave*256 + p*64 + lane (p=0..3), 1024/matrix.
    // decode: row = pg>>3, gcol = (pg&7) ^ (row&7); global ofs = row*ld + gcol*16.
    int aofs[4], bofs[4];
    #pragma unroll
    for (int p = 0; p < 4; p++) {
        int pg = wave * 256 + p * 64 + lane;
        int row = pg >> 3, gcol = (pg & 7) ^ (row & 7);
        aofs[p] = row * lda + gcol * 16;
        bofs[p] = row * ldb + gcol * 16;
    }

    f32x4 acc[4][4];
    #pragma unroll
    for (int mt = 0; mt < 4; mt++)
        #pragma unroll
        for (int nt = 0; nt < 4; nt++)
            acc[mt][nt] = (f32x4)(0.0f);

    const u8* Ab = A  + (size_t)m0 * lda;
    const u8* Bb = BT + (size_t)n0 * ldb;

    union Frag { struct { i32x4 lo, hi; } half; i32x8 v; };

    for (int k0 = 0; k0 < K; k0 += 128) {
        #pragma unroll
        for (int p = 0; p < 4; p++) {
            int base = (wave * 256 + p * 64) * 16;   // wave-uniform LDS byte offset
            load16(Ab + k0 + aofs[p], As + base);
            load16(Bb + k0 + bofs[p], Bs + base);
        }
        __syncthreads();
        Frag fa[4], fb[4];
        #pragma unroll
        for (int t = 0; t < 4; t++) {
            int mA = wm * 64 + t * 16 + lrow;
            int mB = wn * 64 + t * 16 + lrow;
            int sw = lrow & 7;
            fa[t].half.lo = *reinterpret_cast<const i32x4*>(As + (mA * 8 + ((2 * q)     ^ sw)) * 16);
            fa[t].half.hi = *reinterpret_cast<const i32x4*>(As + (mA * 8 + ((2 * q + 1) ^ sw)) * 16);
            fb[t].half.lo = *reinterpret_cast<const i32x4*>(Bs + (mB * 8 + ((2 * q)     ^ sw)) * 16);
            fb[t].half.hi = *reinterpret_cast<const i32x4*>(Bs + (mB * 8 + ((2 * q + 1) ^ sw)) * 16);
        }
        #pragma unroll
        for (int mt = 0; mt < 4; mt++)
            #pragma unroll
            for (int nt = 0; nt < 4; nt++)
                acc[mt][nt] = __builtin_amdgcn_mfma_scale_f32_16x16x128_f8f6f4(
                    fa[mt].v, fb[nt].v, acc[mt][nt],
                    0, 0,                      // cbsz/blgp = fp8 e4m3
                    0, 0x7F7F7F7F,             // A scale: 2^0
                    0, 0x7A7A7A7A);            // B scale: 2^-5
        __syncthreads();
    }

    // C/D layout (16x16): col = lane&15, row = (lane>>4)*4 + reg
    int colg[4]; float bias_v[4];
    #pragma unroll
    for (int nt = 0; nt < 4; nt++) {
        colg[nt] = n0 + wn * 64 + nt * 16 + lrow;
        bias_v[nt] = (colg[nt] < realN) ? bias[colg[nt]] : 0.0f;
    }

    #pragma unroll
    for (int mt = 0; mt < 4; mt++) {
        int rowb = m0 + wm * 64 + mt * 16 + q * 4;
        #pragma unroll
        for (int r = 0; r < 4; r++) {
            int tok = rowb + r;
            if constexpr (LSEP) {
                int tg = tgt[tok];
                float s = 0.0f;
                #pragma unroll
                for (int nt = 0; nt < 4; nt++) {
                    if (colg[nt] < realN) {
                        float logit = acc[mt][nt][r] + bias_v[nt];
                        s += __expf(logit);
                        if (colg[nt] == tg) atomicAdd(&lab[tok], logit);
                    }
                }
                s += __shfl_xor(s, 1);
                s += __shfl_xor(s, 2);
                s += __shfl_xor(s, 4);
                s += __shfl_xor(s, 8);
                if (lrow == 0) atomicAdd(&sumexp[tok], s);
            } else {
                #pragma unroll
                for (int nt = 0; nt < 4; nt++)
                    out[(size_t)tok * ldo + colg[nt]] = to_e4m3(acc[mt][nt][r] + bias_v[nt]);
            }
        }
    }
}

// ---------------- proj GEMM (store epilogue) ----------------
__launch_bounds__(256, 2)
__global__ void gemm_proj(const u8* __restrict__ A, const u8* __restrict__ BT,
                          const float* __restrict__ bias, u8* __restrict__ out) {
    __shared__ __align__(16) u8 As[16384];
    __shared__ __align__(16) u8 Bs[16384];
    gemm_body<false>(A, HID, BT, HID, bias, HID, PREAL,
                     nullptr, nullptr, nullptr, out, PFUSE,
                     blockIdx.x * 128, blockIdx.y * 128, As, Bs);
}

// ---------------- fused LSE GEMM: head + tail0 + tail1 in one dispatch ----------------
struct Seg {
    const u8* A; int lda;
    const u8* BT; int ldb;
    const float* bias; int K; int realN;
    const int* tgt; float* sumexp; float* lab;
    int nblk;
};

__launch_bounds__(256, 2)
__global__ void gemm_lse3(Seg s0, Seg s1, Seg s2) {
    __shared__ __align__(16) u8 As[16384];
    __shared__ __align__(16) u8 Bs[16384];
    int b = blockIdx.x;
    Seg s; int rel;
    if (b < s0.nblk)                { s = s0; rel = b; }
    else if (b < s0.nblk + s1.nblk) { s = s1; rel = b - s0.nblk; }
    else                            { s = s2; rel = b - s0.nblk - s1.nblk; }
    int m0 = (rel & 31) * 128, n0 = (rel >> 5) * 128;
    gemm_body<true>(s.A, s.lda, s.BT, s.ldb, s.bias, s.K, s.realN,
                    s.tgt, s.sumexp, s.lab, nullptr, 0, m0, n0, As, Bs);
}

// =====================================================================
// prep: all casts/transposes/init fused into one dispatch (branch by range)
// =====================================================================
__device__ __forceinline__ void do_transpose(const float* __restrict__ W, u8* __restrict__ WT,
                                             int K, int N, int Kpad, float scale,
                                             int bx, int by, float (*tile)[33]) {
    int n0 = bx * 32, k0 = by * 64;
    int tx = threadIdx.x & 31, ty = threadIdx.x >> 5;   // 32 x 8
    #pragma unroll
    for (int i = 0; i < 8; i++) {
        int k = k0 + ty + i * 8, n = n0 + tx;
        tile[ty + i * 8][tx] = (k < K && n < N) ? W[(size_t)k * N + n] * scale : 0.0f;
    }
    __syncthreads();
    int n = threadIdx.x >> 3, kc = threadIdx.x & 7;     // n 0..31, kc 0..7
    union { u8 b[8]; uint2 u; } v;
    #pragma unroll
    for (int j = 0; j < 8; j++) v.b[j] = to_e4m3(tile[kc * 8 + j][n]);
    *reinterpret_cast<uint2*>(WT + (size_t)(n0 + n) * Kpad + k0 + kc * 8) = v.u;
}

#define NB_HEADT 8064   // 504 x 16
#define NB_T0W   1504   // 376 x 4
#define NB_CAST  1024
#define NB_T1W    504   // 252 x 2
#define NB_T0P    128   // 8 x 16
#define NB_T1P     64   // 4 x 16
#define NB_INIT    16

__global__ void prep_kernel(const float* __restrict__ inp, const int* __restrict__ labels,
                            const float* __restrict__ head_W,
                            const float* __restrict__ t0_pW, const float* __restrict__ t0_pb,
                            const float* __restrict__ t0_W,
                            const float* __restrict__ t1_pW, const float* __restrict__ t1_pb,
                            const float* __restrict__ t1_W,
                            u8* __restrict__ inp_f8, u8* __restrict__ headW8,
                            u8* __restrict__ fpW8, u8* __restrict__ t0W8, u8* __restrict__ t1W8,
                            float* __restrict__ acc6, int* __restrict__ tgts,
                            float* __restrict__ pbias, float* __restrict__ out) {
    __shared__ float tile[64][33];
    int b = blockIdx.x;
    if (b < NB_HEADT) {
        do_transpose(head_W, headW8, HID, NHEAD, HID, 32.0f, b % 504, b / 504, tile);
    } else if (b < NB_HEADT + NB_T0W) {
        int r = b - NB_HEADT;
        do_transpose(t0_W, t0W8, P0, N0, P0, 32.0f, r % 376, r / 376, tile);
    } else if (b < NB_HEADT + NB_T0W + NB_CAST) {
        int r = b - (NB_HEADT + NB_T0W);
        int i = r * 256 + threadIdx.x;          // i < 262144 = M_TOK*HID/4
        float4 v = reinterpret_cast<const float4*>(inp)[i];
        uchar4 o8;
        o8.x = to_e4m3(v.x); o8.y = to_e4m3(v.y); o8.z = to_e4m3(v.z); o8.w = to_e4m3(v.w);
        reinterpret_cast<uchar4*>(inp_f8)[i] = o8;
    } else if (b < NB_HEADT + NB_T0W + NB_CAST + NB_T1W) {
        int r = b - (NB_HEADT + NB_T0W + NB_CAST);
        do_transpose(t1_W, t1W8, P1, N1, 128, 32.0f, r % 252, r / 252, tile);
    } else if (b < NB_HEADT + NB_T0W + NB_CAST + NB_T1W + NB_T0P) {
        int r = b - (NB_HEADT + NB_T0W + NB_CAST + NB_T1W);
        do_transpose(t0_pW, fpW8, HID, P0, HID, 32.0f, r % 8, r / 8, tile);
    } else if (b < NB_HEADT + NB_T0W + NB_CAST + NB_T1W + NB_T0P + NB_T1P) {
        int r = b - (NB_HEADT + NB_T0W + NB_CAST + NB_T1W + NB_T0P);
        do_transpose(t1_pW, fpW8 + 256 * HID, HID, P1, HID, 32.0f, r % 4, r / 4, tile);
    } else {
        int r = b - (NB_HEADT + NB_T0W + NB_CAST + NB_T1W + NB_T0P + NB_T1P);
        int t = r * 256 + threadIdx.x;          // t < 4096
        for (int j = t; j < 6 * M_TOK; j += M_TOK) acc6[j] = 0.0f;
        if (t == 0) out[0] = 0.0f;
        if (t < PFUSE) pbias[t] = (t < 256) ? t0_pb[t] : ((t < PREAL) ? t1_pb[t - 256] : 0.0f);
        int lbl = labels[t];
        tgts[t]             = (lbl < 16000) ? lbl : ((lbl < 28000) ? 16000 : 16001);
        int t0 = lbl - 16000; t0 = t0 < 0 ? 0 : (t0 > 11999 ? 11999 : t0);
        int t1 = lbl - 28000; t1 = t1 < 0 ? 0 : (t1 > 7999  ? 7999  : t1);
        tgts[M_TOK + t]     = t0;
        tgts[2 * M_TOK + t] = t1;
    }
}

// ---------------- finalize: per-token loss, mask, mean ----------------
__global__ void finalize_kernel(const int* __restrict__ labels, const float* __restrict__ acc6,
                                float* __restrict__ out) {
    int t = blockIdx.x * blockDim.x + threadIdx.x;   // 4096 threads
    const float* sumH = acc6;
    const float* labH = acc6 + M_TOK;
    const float* sum0 = acc6 + 2 * M_TOK;
    const float* lab0 = acc6 + 3 * M_TOK;
    const float* sum1 = acc6 + 4 * M_TOK;
    const float* lab1 = acc6 + 5 * M_TOK;
    int lbl = labels[t];
    float l = 0.0f;
    if (lbl != 0) {
        l = logf(sumH[t]) - labH[t];
        if (lbl >= 16000 && lbl < 28000) l += logf(sum0[t]) - lab0[t];
        else if (lbl >= 28000)           l += logf(sum1[t]) - lab1[t];
    }
    l *= (1.0f / (float)M_TOK);
    #pragma unroll
    for (int off = 1; off < 64; off <<= 1) l += __shfl_xor(l, off);
    __shared__ float red[4];
    if ((threadIdx.x & 63) == 0) red[threadIdx.x >> 6] = l;
    __syncthreads();
    if (threadIdx.x == 0) atomicAdd(out, red[0] + red[1] + red[2] + red[3]);
}

// ---------------- host launcher ----------------
extern "C" void kernel_launch(void* const* d_in, const int* in_sizes, int n_in,
                              void* d_out, int out_size, void* d_ws, size_t ws_size,
                              hipStream_t stream) {
    const float* inp    = (const float*)d_in[0];
    const int*   labels = (const int*)  d_in[1];
    const float* head_W = (const float*)d_in[2];
    const float* head_b = (const float*)d_in[3];
    const float* t0_pW  = (const float*)d_in[4];
    const float* t0_pb  = (const float*)d_in[5];
    const float* t0_W   = (const float*)d_in[6];
    const float* t0_b   = (const float*)d_in[7];
    const float* t1_pW  = (const float*)d_in[8];
    const float* t1_pb  = (const float*)d_in[9];
    const float* t1_W   = (const float*)d_in[10];
    const float* t1_b   = (const float*)d_in[11];
    float* out = (float*)d_out;

    char* ws = (char*)d_ws;
    size_t off = 0;
    auto alloc = [&](size_t bytes) { char* p = ws + off; off += (bytes + 255) & ~(size_t)255; return p; };
    u8*    inp_f8  = (u8*)   alloc((size_t)M_TOK * HID);
    u8*    headW8  = (u8*)   alloc((size_t)NHEAD_PAD * HID);
    u8*    fpW8    = (u8*)   alloc((size_t)PFUSE * HID);
    u8*    t0W8    = (u8*)   alloc((size_t)N0_PAD * P0);
    u8*    t1W8    = (u8*)   alloc((size_t)N1_PAD * 128);
    u8*    proj8   = (u8*)   alloc((size_t)M_TOK * PFUSE);
    float* acc6    = (float*)alloc(6 * M_TOK * 4);
    int*   tgts    = (int*)  alloc(3 * M_TOK * 4);
    float* pbias   = (float*)alloc(PFUSE * 4);

    // stage 1: all conversions / transposes / init in one dispatch
    int nb = NB_HEADT + NB_T0W + NB_CAST + NB_T1W + NB_T0P + NB_T1P + NB_INIT;
    prep_kernel<<<nb, 256, 0, stream>>>(inp, labels, head_W, t0_pW, t0_pb, t0_W,
                                        t1_pW, t1_pb, t1_W,
                                        inp_f8, headW8, fpW8, t0W8, t1W8,
                                        acc6, tgts, pbias, out);

    // stage 2: fused tail projections -> fp8 [M_TOK x 384]
    gemm_proj<<<dim3(M_TOK / 128, PFUSE / 128), 256, 0, stream>>>(inp_f8, fpW8, pbias, proj8);

    // stage 3: all three LSE GEMMs in one dispatch (head first = longest)
    Seg s0{inp_f8,      HID,   headW8, HID, head_b, HID, NHEAD, tgts,             acc6,             acc6 + M_TOK,     32 * (NHEAD_PAD / 128)};
    Seg s1{proj8,       PFUSE, t0W8,   P0,  t0_b,   P0,  N0,    tgts + M_TOK,     acc6 + 2 * M_TOK, acc6 + 3 * M_TOK, 32 * (N0_PAD / 128)};
    Seg s2{proj8 + 256, PFUSE, t1W8,   128, t1_b,   128, N1,    tgts + 2 * M_TOK, acc6 + 4 * M_TOK, acc6 + 5 * M_TOK, 32 * (N1_PAD / 128)};
    gemm_lse3<<<s0.nblk + s1.nblk + s2.nblk, 256, 0, stream>>>(s0, s1, s2);

    // stage 4: reduce to scalar mean
    finalize_kernel<<<M_TOK / 256, 256, 0, stream>>>(labels, acc6, out);
}

// Round 9
// 367.633 us; speedup vs baseline: 1.3310x; 1.0257x over previous
//
#include <hip/hip_runtime.h>
#include <hip/hip_bf16.h>
#include <hip/hip_fp8.h>
#include <cstdint>
#include <cstddef>

// ---------------- problem constants ----------------
#define M_TOK 4096          // B*S = 4*1024 tokens
#define HID   1024
#define NHEAD 16002
#define NHEAD_PAD 16128     // 126*128
#define P0    256
#define N0    12000
#define N0_PAD 12032        // 94*128
#define P1    64
#define N1    8000
#define N1_PAD 8192         // 64*128 (padded to even tile count for swizzle)
#define PFUSE 384           // fused proj width: 256 + 128(pad of 64)
#define PREAL 320           // real cols in fused proj: 256 + 64

typedef unsigned char u8;
typedef float f32x4 __attribute__((ext_vector_type(4)));
typedef int   i32x4 __attribute__((ext_vector_type(4)));
typedef int   i32x8 __attribute__((ext_vector_type(8)));

// async global->LDS, 16B per lane; lds ptr = wave-uniform base, HW scatters lane*16.
__device__ __forceinline__ void load16(const void* g, void* l) {
    __builtin_amdgcn_global_load_lds(
        (__attribute__((address_space(1))) void*)g,
        (__attribute__((address_space(3))) void*)l,
        16, 0, 0);
}

__device__ __forceinline__ u8 to_e4m3(float f) {
    __hip_fp8_e4m3 h(f);
    return (u8)h.__x;
}

// =====================================================================
// Unified MX-fp8 GEMM body: C = A(M x K, lda) * BT(N x K, ldb)^T
// mfma_scale_f32_16x16x128_f8f6f4 (R5-verified); A-scale 1.0, B-scale 2^-5.
// Block 128x128, BK=128, 4 waves 2x2, wave 64x64 via 4x4 MFMAs (16 indep chains).
// LDS per matrix: flat 128 rows x 128 B; physical granule = row*8 + (gcol ^ (row&7)).
// =====================================================================
template <bool LSEP>
__device__ __forceinline__ void gemm_body(
        const u8* __restrict__ A, int lda, const u8* __restrict__ BT, int ldb,
        const float* __restrict__ bias, int K, int realN,
        const int* __restrict__ tgt, float* __restrict__ sumexp, float* __restrict__ lab,
        u8* __restrict__ out, int ldo, int m0, int n0,
        u8* As, u8* Bs) {
    const int tid  = threadIdx.x;
    const int lane = tid & 63;
    const int wave = tid >> 6;
    const int wm = wave >> 1, wn = wave & 1;
    const int q = lane >> 4, lrow = lane & 15;

    // staging: physical granule pg = wave*256 + p*64 + lane (p=0..3), 1024/matrix.
    // decode: row = pg>>3, gcol = (pg&7) ^ (row&7); global ofs = row*ld + gcol*16.
    int aofs[4], bofs[4];
    #pragma unroll
    for (int p = 0; p < 4; p++) {
        int pg = wave * 256 + p * 64 + lane;
        int row = pg >> 3, gcol = (pg & 7) ^ (row & 7);
        aofs[p] = row * lda + gcol * 16;
        bofs[p] = row * ldb + gcol * 16;
    }

    f32x4 acc[4][4];
    #pragma unroll
    for (int mt = 0; mt < 4; mt++)
        #pragma unroll
        for (int nt = 0; nt < 4; nt++)
            acc[mt][nt] = (f32x4)(0.0f);

    const u8* Ab = A  + (size_t)m0 * lda;
    const u8* Bb = BT + (size_t)n0 * ldb;

    union Frag { struct { i32x4 lo, hi; } half; i32x8 v; };

    for (int k0 = 0; k0 < K; k0 += 128) {
        #pragma unroll
        for (int p = 0; p < 4; p++) {
            int base = (wave * 256 + p * 64) * 16;   // wave-uniform LDS byte offset
            load16(Ab + k0 + aofs[p], As + base);
            load16(Bb + k0 + bofs[p], Bs + base);
        }
        __syncthreads();
        Frag fa[4], fb[4];
        #pragma unroll
        for (int t = 0; t < 4; t++) {
            int mA = wm * 64 + t * 16 + lrow;
            int mB = wn * 64 + t * 16 + lrow;
            int sw = lrow & 7;
            fa[t].half.lo = *reinterpret_cast<const i32x4*>(As + (mA * 8 + ((2 * q)     ^ sw)) * 16);
            fa[t].half.hi = *reinterpret_cast<const i32x4*>(As + (mA * 8 + ((2 * q + 1) ^ sw)) * 16);
            fb[t].half.lo = *reinterpret_cast<const i32x4*>(Bs + (mB * 8 + ((2 * q)     ^ sw)) * 16);
            fb[t].half.hi = *reinterpret_cast<const i32x4*>(Bs + (mB * 8 + ((2 * q + 1) ^ sw)) * 16);
        }
        #pragma unroll
        for (int mt = 0; mt < 4; mt++)
            #pragma unroll
            for (int nt = 0; nt < 4; nt++)
                acc[mt][nt] = __builtin_amdgcn_mfma_scale_f32_16x16x128_f8f6f4(
                    fa[mt].v, fb[nt].v, acc[mt][nt],
                    0, 0,                      // cbsz/blgp = fp8 e4m3
                    0, 0x7F7F7F7F,             // A scale: 2^0
                    0, 0x7A7A7A7A);            // B scale: 2^-5
        __syncthreads();
    }

    // C/D layout (16x16): col = lane&15, row = (lane>>4)*4 + reg
    int colg[4]; float bias_v[4];
    #pragma unroll
    for (int nt = 0; nt < 4; nt++) {
        colg[nt] = n0 + wn * 64 + nt * 16 + lrow;
        bias_v[nt] = (colg[nt] < realN) ? bias[colg[nt]] : 0.0f;
    }

    #pragma unroll
    for (int mt = 0; mt < 4; mt++) {
        int rowb = m0 + wm * 64 + mt * 16 + q * 4;
        #pragma unroll
        for (int r = 0; r < 4; r++) {
            int tok = rowb + r;
            if constexpr (LSEP) {
                int tg = tgt[tok];
                float s = 0.0f;
                #pragma unroll
                for (int nt = 0; nt < 4; nt++) {
                    if (colg[nt] < realN) {
                        float logit = acc[mt][nt][r] + bias_v[nt];
                        s += __expf(logit);
                        if (colg[nt] == tg) atomicAdd(&lab[tok], logit);
                    }
                }
                s += __shfl_xor(s, 1);
                s += __shfl_xor(s, 2);
                s += __shfl_xor(s, 4);
                s += __shfl_xor(s, 8);
                if (lrow == 0) atomicAdd(&sumexp[tok], s);
            } else {
                #pragma unroll
                for (int nt = 0; nt < 4; nt++)
                    out[(size_t)tok * ldo + colg[nt]] = to_e4m3(acc[mt][nt][r] + bias_v[nt]);
            }
        }
    }
}

// ---------------- proj GEMM (store epilogue) ----------------
__launch_bounds__(256, 2)
__global__ void gemm_proj(const u8* __restrict__ A, const u8* __restrict__ BT,
                          const float* __restrict__ bias, u8* __restrict__ out) {
    __shared__ __align__(16) u8 As[16384];
    __shared__ __align__(16) u8 Bs[16384];
    gemm_body<false>(A, HID, BT, HID, bias, HID, PREAL,
                     nullptr, nullptr, nullptr, out, PFUSE,
                     blockIdx.x * 128, blockIdx.y * 128, As, Bs);
}

// ---------------- fused LSE GEMM: head + tail0 + tail1 in one dispatch ----------------
struct Seg {
    const u8* A; int lda;
    const u8* BT; int ldb;
    const float* bias; int K; int realN;
    const int* tgt; float* sumexp; float* lab;
    int nblk;   // 32 m-tiles x NT n-tiles, NT even; nblk % 64 == 0
};

__launch_bounds__(256, 2)
__global__ void gemm_lse3(Seg s0, Seg s1, Seg s2) {
    __shared__ __align__(16) u8 As[16384];
    __shared__ __align__(16) u8 Bs[16384];
    int b = blockIdx.x;
    Seg s; int rel;
    if (b < s0.nblk)                { s = s0; rel = b; }
    else if (b < s0.nblk + s1.nblk) { s = s1; rel = b - s0.nblk; }
    else                            { s = s2; rel = b - s0.nblk - s1.nblk; }
    // L2-locality swizzle: 64-block groups = 32 m-tiles x 2 n-tiles.
    int pair = rel >> 6, inner = rel & 63;
    int m0 = (inner >> 1) * 128;
    int n0 = (pair * 2 + (inner & 1)) * 128;
    gemm_body<true>(s.A, s.lda, s.BT, s.ldb, s.bias, s.K, s.realN,
                    s.tgt, s.sumexp, s.lab, nullptr, 0, m0, n0, As, Bs);
}

// =====================================================================
// prep: all casts/transposes/init fused into one dispatch (branch by range)
// 64x64 transpose tiles: 256B-segment f32 reads, 16B/lane fp8 stores.
// =====================================================================
__device__ __forceinline__ void do_transpose(const float* __restrict__ W, u8* __restrict__ WT,
                                             int K, int N, int Kpad, float scale,
                                             int bx, int by, float (*tile)[65]) {
    int n0 = bx * 64, k0 = by * 64;
    int tx = threadIdx.x & 63, ty = threadIdx.x >> 6;   // 64 x 4
    #pragma unroll
    for (int i = 0; i < 16; i++) {
        int k = k0 + ty + i * 4, n = n0 + tx;
        tile[ty + i * 4][tx] = (k < K && n < N) ? W[(size_t)k * N + n] * scale : 0.0f;
    }
    __syncthreads();
    int n = threadIdx.x >> 2, kb = (threadIdx.x & 3) * 16;   // n 0..63, kb 0/16/32/48
    union { u8 b[16]; uint4 u; } v;
    #pragma unroll
    for (int j = 0; j < 16; j++) v.b[j] = to_e4m3(tile[kb + j][n]);
    *reinterpret_cast<uint4*>(WT + (size_t)(n0 + n) * Kpad + k0 + kb) = v.u;
}

#define NBT_HEAD 4032   // 252 x 16
#define NBT_CAST 1024
#define NBT_T0W   752   // 188 x 4
#define NBT_T1W   256   // 128 x 2
#define NBT_T0P    64   // 4 x 16
#define NBT_T1P    32   // 2 x 16
#define NBT_INIT   16

__global__ void prep_kernel(const float* __restrict__ inp, const int* __restrict__ labels,
                            const float* __restrict__ head_W,
                            const float* __restrict__ t0_pW, const float* __restrict__ t0_pb,
                            const float* __restrict__ t0_W,
                            const float* __restrict__ t1_pW, const float* __restrict__ t1_pb,
                            const float* __restrict__ t1_W,
                            u8* __restrict__ inp_f8, u8* __restrict__ headW8,
                            u8* __restrict__ fpW8, u8* __restrict__ t0W8, u8* __restrict__ t1W8,
                            float* __restrict__ acc6, int* __restrict__ tgts,
                            float* __restrict__ pbias, float* __restrict__ out) {
    __shared__ float tile[64][65];
    int b = blockIdx.x;
    if (b < NBT_HEAD) {
        do_transpose(head_W, headW8, HID, NHEAD, HID, 32.0f, b % 252, b / 252, tile);
    } else if (b < NBT_HEAD + NBT_CAST) {
        int r = b - NBT_HEAD;
        int i = r * 256 + threadIdx.x;          // i < 262144 = M_TOK*HID/4
        float4 v = reinterpret_cast<const float4*>(inp)[i];
        uchar4 o8;
        o8.x = to_e4m3(v.x); o8.y = to_e4m3(v.y); o8.z = to_e4m3(v.z); o8.w = to_e4m3(v.w);
        reinterpret_cast<uchar4*>(inp_f8)[i] = o8;
    } else if (b < NBT_HEAD + NBT_CAST + NBT_T0W) {
        int r = b - (NBT_HEAD + NBT_CAST);
        do_transpose(t0_W, t0W8, P0, N0, P0, 32.0f, r % 188, r / 188, tile);
    } else if (b < NBT_HEAD + NBT_CAST + NBT_T0W + NBT_T1W) {
        int r = b - (NBT_HEAD + NBT_CAST + NBT_T0W);
        do_transpose(t1_W, t1W8, P1, N1, 128, 32.0f, r % 128, r / 128, tile);
    } else if (b < NBT_HEAD + NBT_CAST + NBT_T0W + NBT_T1W + NBT_T0P) {
        int r = b - (NBT_HEAD + NBT_CAST + NBT_T0W + NBT_T1W);
        do_transpose(t0_pW, fpW8, HID, P0, HID, 32.0f, r % 4, r / 4, tile);
    } else if (b < NBT_HEAD + NBT_CAST + NBT_T0W + NBT_T1W + NBT_T0P + NBT_T1P) {
        int r = b - (NBT_HEAD + NBT_CAST + NBT_T0W + NBT_T1W + NBT_T0P);
        do_transpose(t1_pW, fpW8 + 256 * HID, HID, P1, HID, 32.0f, r % 2, r / 2, tile);
    } else {
        int r = b - (NBT_HEAD + NBT_CAST + NBT_T0W + NBT_T1W + NBT_T0P + NBT_T1P);
        int t = r * 256 + threadIdx.x;          // t < 4096
        for (int j = t; j < 6 * M_TOK; j += M_TOK) acc6[j] = 0.0f;
        if (t == 0) out[0] = 0.0f;
        if (t < PFUSE) pbias[t] = (t < 256) ? t0_pb[t] : ((t < PREAL) ? t1_pb[t - 256] : 0.0f);
        int lbl = labels[t];
        tgts[t]             = (lbl < 16000) ? lbl : ((lbl < 28000) ? 16000 : 16001);
        int t0 = lbl - 16000; t0 = t0 < 0 ? 0 : (t0 > 11999 ? 11999 : t0);
        int t1 = lbl - 28000; t1 = t1 < 0 ? 0 : (t1 > 7999  ? 7999  : t1);
        tgts[M_TOK + t]     = t0;
        tgts[2 * M_TOK + t] = t1;
    }
}

// ---------------- finalize: per-token loss, mask, mean ----------------
__global__ void finalize_kernel(const int* __restrict__ labels, const float* __restrict__ acc6,
                                float* __restrict__ out) {
    int t = blockIdx.x * blockDim.x + threadIdx.x;   // 4096 threads
    const float* sumH = acc6;
    const float* labH = acc6 + M_TOK;
    const float* sum0 = acc6 + 2 * M_TOK;
    const float* lab0 = acc6 + 3 * M_TOK;
    const float* sum1 = acc6 + 4 * M_TOK;
    const float* lab1 = acc6 + 5 * M_TOK;
    int lbl = labels[t];
    float l = 0.0f;
    if (lbl != 0) {
        l = logf(sumH[t]) - labH[t];
        if (lbl >= 16000 && lbl < 28000) l += logf(sum0[t]) - lab0[t];
        else if (lbl >= 28000)           l += logf(sum1[t]) - lab1[t];
    }
    l *= (1.0f / (float)M_TOK);
    #pragma unroll
    for (int off = 1; off < 64; off <<= 1) l += __shfl_xor(l, off);
    __shared__ float red[4];
    if ((threadIdx.x & 63) == 0) red[threadIdx.x >> 6] = l;
    __syncthreads();
    if (threadIdx.x == 0) atomicAdd(out, red[0] + red[1] + red[2] + red[3]);
}

// ---------------- host launcher ----------------
extern "C" void kernel_launch(void* const* d_in, const int* in_sizes, int n_in,
                              void* d_out, int out_size, void* d_ws, size_t ws_size,
                              hipStream_t stream) {
    const float* inp    = (const float*)d_in[0];
    const int*   labels = (const int*)  d_in[1];
    const float* head_W = (const float*)d_in[2];
    const float* head_b = (const float*)d_in[3];
    const float* t0_pW  = (const float*)d_in[4];
    const float* t0_pb  = (const float*)d_in[5];
    const float* t0_W   = (const float*)d_in[6];
    const float* t0_b   = (const float*)d_in[7];
    const float* t1_pW  = (const float*)d_in[8];
    const float* t1_pb  = (const float*)d_in[9];
    const float* t1_W   = (const float*)d_in[10];
    const float* t1_b   = (const float*)d_in[11];
    float* out = (float*)d_out;

    char* ws = (char*)d_ws;
    size_t off = 0;
    auto alloc = [&](size_t bytes) { char* p = ws + off; off += (bytes + 255) & ~(size_t)255; return p; };
    u8*    inp_f8  = (u8*)   alloc((size_t)M_TOK * HID);
    u8*    headW8  = (u8*)   alloc((size_t)NHEAD_PAD * HID);
    u8*    fpW8    = (u8*)   alloc((size_t)PFUSE * HID);
    u8*    t0W8    = (u8*)   alloc((size_t)N0_PAD * P0);
    u8*    t1W8    = (u8*)   alloc((size_t)N1_PAD * 128);
    u8*    proj8   = (u8*)   alloc((size_t)M_TOK * PFUSE);
    float* acc6    = (float*)alloc(6 * M_TOK * 4);
    int*   tgts    = (int*)  alloc(3 * M_TOK * 4);
    float* pbias   = (float*)alloc(PFUSE * 4);

    // stage 1: all conversions / transposes / init in one dispatch
    int nb = NBT_HEAD + NBT_CAST + NBT_T0W + NBT_T1W + NBT_T0P + NBT_T1P + NBT_INIT;
    prep_kernel<<<nb, 256, 0, stream>>>(inp, labels, head_W, t0_pW, t0_pb, t0_W,
                                        t1_pW, t1_pb, t1_W,
                                        inp_f8, headW8, fpW8, t0W8, t1W8,
                                        acc6, tgts, pbias, out);

    // stage 2: fused tail projections -> fp8 [M_TOK x 384]
    gemm_proj<<<dim3(M_TOK / 128, PFUSE / 128), 256, 0, stream>>>(inp_f8, fpW8, pbias, proj8);

    // stage 3: all three LSE GEMMs in one dispatch (head first = longest)
    Seg s0{inp_f8,      HID,   headW8, HID, head_b, HID, NHEAD, tgts,             acc6,             acc6 + M_TOK,     32 * (NHEAD_PAD / 128)};
    Seg s1{proj8,       PFUSE, t0W8,   P0,  t0_b,   P0,  N0,    tgts + M_TOK,     acc6 + 2 * M_TOK, acc6 + 3 * M_TOK, 32 * (N0_PAD / 128)};
    Seg s2{proj8 + 256, PFUSE, t1W8,   128, t1_b,   128, N1,    tgts + 2 * M_TOK, acc6 + 4 * M_TOK, acc6 + 5 * M_TOK, 32 * (N1_PAD / 128)};
    gemm_lse3<<<s0.nblk + s1.nblk + s2.nblk, 256, 0, stream>>>(s0, s1, s2);

    // stage 4: reduce to scalar mean
    finalize_kernel<<<M_TOK / 256, 256, 0, stream>>>(labels, acc6, out);
}